// Round 6
// baseline (1008.764 us; speedup 1.0000x reference)
//
#include <hip/hip_runtime.h>
#include <hip/hip_bf16.h>

#define NU 100000
#define NM 20000
#define DD 64
#define RR 5
#define EE 400000
#define NE (RR * EE)            // 2,000,000 edges per direction
#define NNODE (NM + NU)         // 120,000 destination bins (movies first)
#define NTILE (EE / 16)         // 25,000 16-edge tiles per relation

typedef __attribute__((ext_vector_type(8))) short bf16x8;
typedef __attribute__((ext_vector_type(8))) short s16x8;
typedef __attribute__((ext_vector_type(4))) float f32x4;

static __device__ __forceinline__ short f2bf(float f) {
  return __builtin_bit_cast(short, __float2bfloat16(f));
}
static __device__ __forceinline__ float bf2f(short s) {
  return __builtin_bit_cast(float, ((unsigned)(unsigned short)s) << 16);
}

static __device__ __forceinline__ bf16x8 pack8(const float4 a, const float4 b) {
  bf16x8 o;
  o[0] = f2bf(a.x); o[1] = f2bf(a.y); o[2] = f2bf(a.z); o[3] = f2bf(a.w);
  o[4] = f2bf(b.x); o[5] = f2bf(b.y); o[6] = f2bf(b.z); o[7] = f2bf(b.w);
  return o;
}
static __device__ __forceinline__ bf16x8 cvt8(const float* __restrict__ p) {
  return pack8(*(const float4*)p, *(const float4*)(p + 4));
}

static __device__ __forceinline__ float sigm(float x) { return 1.f / (1.f + __expf(-x)); }
static __device__ __forceinline__ float gelu(float x) {
  return 0.5f * x * (1.f + erff(x * 0.70710678118654752f));
}

// ---------------------------------------------------------------------------
// rank0: ONE atomic pass. cnt (zeroed) -> per-edge rank within destination,
// and cnt ends up holding the per-node degree (input to scanoff).
// ---------------------------------------------------------------------------
__global__ __launch_bounds__(256) void rank0_k(const int* __restrict__ eu,
                                               const int* __restrict__ em,
                                               int* __restrict__ cnt,
                                               int* __restrict__ rank_m,
                                               int* __restrict__ rank_u) {
  const int i = (blockIdx.x * 256 + threadIdx.x) * 4;
  if (i < NE) {
    const int4 a = *(const int4*)(em + i);
    const int4 b = *(const int4*)(eu + i);
    int4 rm, ru;
    rm.x = atomicAdd(&cnt[a.x], 1);
    rm.y = atomicAdd(&cnt[a.y], 1);
    rm.z = atomicAdd(&cnt[a.z], 1);
    rm.w = atomicAdd(&cnt[a.w], 1);
    ru.x = atomicAdd(&cnt[NM + b.x], 1);
    ru.y = atomicAdd(&cnt[NM + b.y], 1);
    ru.z = atomicAdd(&cnt[NM + b.z], 1);
    ru.w = atomicAdd(&cnt[NM + b.w], 1);
    *(int4*)(rank_m + i) = rm;
    *(int4*)(rank_u + i) = ru;
  }
}

__global__ __launch_bounds__(1024) void scanoff_k(const int* __restrict__ cnt,
                                                  int* __restrict__ off) {
  __shared__ int sums[1024];
  const int t = threadIdx.x;
  const int ch = (NNODE + 1023) >> 10;    // 118
  const int b0 = t * ch;
  int s = 0;
  for (int i = 0; i < ch; ++i) { int idx = b0 + i; if (idx < NNODE) s += cnt[idx]; }
  sums[t] = s;
  __syncthreads();
  for (int d = 1; d < 1024; d <<= 1) {
    int x = (t >= d) ? sums[t - d] : 0;
    __syncthreads();
    sums[t] += x;
    __syncthreads();
  }
  int run = (t > 0) ? sums[t - 1] : 0;
  for (int i = 0; i < ch; ++i) {
    int idx = b0 + i;
    if (idx < NNODE) { off[idx] = run; run += cnt[idx]; }
  }
  if (t == 1023) off[NNODE] = sums[1023];
}

// ---------------------------------------------------------------------------
// Main fused MFMA kernel, 3-stage software pipeline:
//   RAW(t+2) -> GATHER_W(t+1) -> COMPUTE(t)
// W-row gather latency (~500cyc, L3) is covered by one full tile of compute.
// Column permutation: tile t, col c -> output dim d = 4*c + t.
// ---------------------------------------------------------------------------
#define RAW_M(tile, fA, iEv)                                                  \
  {                                                                           \
    const int e0_ = (tile) * 16;                                              \
    const float* arow_ = rfeat + ((size_t)r * EE + e0_ + c) * DD + kr * 8;    \
    fA[0] = *(const float4*)arow_;                                            \
    fA[1] = *(const float4*)(arow_ + 4);                                      \
    fA[2] = *(const float4*)(arow_ + 32);                                     \
    fA[3] = *(const float4*)(arow_ + 36);                                     \
    const int eb_ = r * EE + e0_ + kr * 4;                                    \
    iEv[0] = *(const int4*)(edges_u + eb_);                                   \
    iEv[1] = *(const int4*)(edges_m + eb_);                                   \
    iEv[2] = *(const int4*)(rank_m + eb_);                                    \
    iEv[3] = *(const int4*)(rank_u + eb_);                                    \
  }

#define GATHW_M(iEv, hu, hm)                                                  \
  {                                                                           \
    const int eus_[4] = {iEv[0].x, iEv[0].y, iEv[0].z, iEv[0].w};             \
    const int ems_[4] = {iEv[1].x, iEv[1].y, iEv[1].z, iEv[1].w};             \
    _Pragma("unroll")                                                         \
    for (int q = 0; q < 4; ++q) {                                             \
      hu[q] = *(const float4*)(W_user  + ((size_t)r * NU + eus_[q]) * DD + 4 * c); \
      hm[q] = *(const float4*)(W_movie + ((size_t)r * NM + ems_[q]) * DD + 4 * c); \
    }                                                                         \
  }

#define COMPUTE_M(fA, iEv, hu, hm)                                            \
  {                                                                           \
    const int eus_[4] = {iEv[0].x, iEv[0].y, iEv[0].z, iEv[0].w};             \
    const int ems_[4] = {iEv[1].x, iEv[1].y, iEv[1].z, iEv[1].w};             \
    const int rms_[4] = {iEv[2].x, iEv[2].y, iEv[2].z, iEv[2].w};             \
    const int rus_[4] = {iEv[3].x, iEv[3].y, iEv[3].z, iEv[3].w};             \
    int slm_[4], slu_[4];                                                     \
    float cju_[4], cjm_[4];                                                   \
    _Pragma("unroll")                                                         \
    for (int q = 0; q < 4; ++q) {                                             \
      slm_[q] = off[ems_[q]] + rms_[q];                                       \
      slu_[q] = off[NM + eus_[q]] + rus_[q];                                  \
      cju_[q] = user_cj[eus_[q]];                                             \
      cjm_[q] = movie_cj[ems_[q]];                                            \
    }                                                                         \
    const bf16x8 A0 = pack8(fA[0], fA[1]);                                    \
    const bf16x8 A1 = pack8(fA[2], fA[3]);                                    \
    f32x4 z4 = {0.f, 0.f, 0.f, 0.f};                                          \
    f32x4 Cu[4], Cm[4], Cs;                                                   \
    _Pragma("unroll")                                                         \
    for (int t = 0; t < 4; ++t) { Cu[t] = z4; Cm[t] = z4; }                   \
    Cs = z4;                                                                  \
    _Pragma("unroll")                                                         \
    for (int t = 0; t < 4; ++t) {                                             \
      Cu[t] = __builtin_amdgcn_mfma_f32_16x16x32_bf16(A0, Bu[t][0], Cu[t], 0, 0, 0); \
      Cu[t] = __builtin_amdgcn_mfma_f32_16x16x32_bf16(A1, Bu[t][1], Cu[t], 0, 0, 0); \
      Cm[t] = __builtin_amdgcn_mfma_f32_16x16x32_bf16(A0, Bm[t][0], Cm[t], 0, 0, 0); \
      Cm[t] = __builtin_amdgcn_mfma_f32_16x16x32_bf16(A1, Bm[t][1], Cm[t], 0, 0, 0); \
    }                                                                         \
    Cs = __builtin_amdgcn_mfma_f32_16x16x32_bf16(A0, Bs[0], Cs, 0, 0, 0);     \
    Cs = __builtin_amdgcn_mfma_f32_16x16x32_bf16(A1, Bs[1], Cs, 0, 0, 0);     \
    _Pragma("unroll")                                                         \
    for (int q = 0; q < 4; ++q) {                                             \
      const int src_ = (lane & 48);                                           \
      const float su_ = __shfl(Cs[q], src_);                                  \
      const float pu_ = __shfl(Cs[q], src_ | 1);                              \
      const float sm_ = __shfl(Cs[q], src_ | 2);                              \
      const float pm_ = __shfl(Cs[q], src_ | 3);                              \
      const float sgu_ = sigm(su_), pau_ = sigm(pu_);                         \
      const float sgmm_ = sigm(sm_), pam_ = sigm(pm_);                        \
      short4 vm_, vu_;                                                        \
      vm_.x = f2bf((hu[q].x * pau_ + Cu[0][q] * sgu_) * cju_[q]);             \
      vm_.y = f2bf((hu[q].y * pau_ + Cu[1][q] * sgu_) * cju_[q]);             \
      vm_.z = f2bf((hu[q].z * pau_ + Cu[2][q] * sgu_) * cju_[q]);             \
      vm_.w = f2bf((hu[q].w * pau_ + Cu[3][q] * sgu_) * cju_[q]);             \
      vu_.x = f2bf((hm[q].x * pam_ + Cm[0][q] * sgmm_) * cjm_[q]);            \
      vu_.y = f2bf((hm[q].y * pam_ + Cm[1][q] * sgmm_) * cjm_[q]);            \
      vu_.z = f2bf((hm[q].z * pam_ + Cm[2][q] * sgmm_) * cjm_[q]);            \
      vu_.w = f2bf((hm[q].w * pam_ + Cm[3][q] * sgmm_) * cjm_[q]);            \
      *(short4*)(msg + ((size_t)slm_[q] << 6) + 4 * c) = vm_;                 \
      *(short4*)(msg + ((size_t)slu_[q] << 6) + 4 * c) = vu_;                 \
    }                                                                         \
  }

__global__ __launch_bounds__(256) void gcmc_main(
    const int* __restrict__ edges_u, const int* __restrict__ edges_m,
    const float* __restrict__ rfeat,
    const float* __restrict__ W_user, const float* __restrict__ W_movie,
    const float* __restrict__ ps_u, const float* __restrict__ rs_u, const float* __restrict__ rw_u,
    const float* __restrict__ ps_m, const float* __restrict__ rs_m, const float* __restrict__ rw_m,
    const float* __restrict__ user_cj, const float* __restrict__ movie_cj,
    const int* __restrict__ rank_m, const int* __restrict__ rank_u,
    const int* __restrict__ off,
    short* __restrict__ msg)
{
  const int r    = blockIdx.y;
  const int lane = threadIdx.x & 63;
  const int wid  = threadIdx.x >> 6;
  const int c    = lane & 15;
  const int kr   = lane >> 4;
  const int wtile = blockIdx.x * 4 + wid;
  if (wtile >= NTILE / 8) return;
  const int wt8 = wtile * 8;

  // ---- B fragments in registers (bf16), loaded once per wave ----
  bf16x8 Bu[4][2], Bm[4][2], Bs[2];
#pragma unroll
  for (int t = 0; t < 4; ++t) {
#pragma unroll
    for (int s = 0; s < 2; ++s) {
      Bu[t][s] = cvt8(rw_u + ((size_t)r * DD + (4 * c + t)) * DD + s * 32 + kr * 8);
      Bm[t][s] = cvt8(rw_m + ((size_t)r * DD + (4 * c + t)) * DD + s * 32 + kr * 8);
    }
  }
#pragma unroll
  for (int s = 0; s < 2; ++s) {
    if (c < 4) {
      const float* v = (c == 0 ? rs_u : c == 1 ? ps_u : c == 2 ? rs_m : ps_m)
                       + r * DD + s * 32 + kr * 8;
      Bs[s] = cvt8(v);
    } else {
      bf16x8 z = {0, 0, 0, 0, 0, 0, 0, 0};
      Bs[s] = z;
    }
  }

  // ---- pipeline buffers (all statically indexed) ----
  float4 fA0[4], fA1[4];
  int4   iE0[4], iE1[4];
  float4 hu0[4], hm0[4], hu1[4], hm1[4];

  RAW_M(wt8 + 0, fA0, iE0);
  RAW_M(wt8 + 1, fA1, iE1);
  GATHW_M(iE0, hu0, hm0);                 // startup stall on E(0) only

#pragma unroll 1
  for (int tt = 0; tt < 8; tt += 2) {
    GATHW_M(iE1, hu1, hm1);               // W for tile tt+1 (covered by COMPUTE tt)
    COMPUTE_M(fA0, iE0, hu0, hm0);        // tile tt
    if (tt < 6) RAW_M(wt8 + tt + 2, fA0, iE0);
    COMPUTE_M(fA1, iE1, hu1, hm1);        // tile tt+1 (covers E(tt+2) latency)
    if (tt < 6) {
      GATHW_M(iE0, hu0, hm0);             // W for tile tt+2 (covered by next COMPUTE)
      RAW_M(wt8 + tt + 3, fA1, iE1);
    }
  }
}

// ---------------------------------------------------------------------------
// Gather-reduce, movies: one wave per movie (avg deg 100).
// 8 lanes per row (16 B/lane b128 loads), 8 rows x 4-deep in flight.
// ---------------------------------------------------------------------------
__global__ __launch_bounds__(256) void gather_m_k(const int* __restrict__ off,
                                                  const short* __restrict__ msg,
                                                  float* __restrict__ out)
{
  const int w    = blockIdx.x * 4 + (threadIdx.x >> 6);   // movie id
  const int lane = threadIdx.x & 63;
  const int sub  = lane >> 3;    // row group 0..7
  const int c8   = lane & 7;     // 16-byte chunk

  const int s0 = off[w];
  const int e1 = off[w + 1];

  float a0[8] = {0,0,0,0,0,0,0,0};
  float a1[8] = {0,0,0,0,0,0,0,0};
  float a2[8] = {0,0,0,0,0,0,0,0};
  float a3[8] = {0,0,0,0,0,0,0,0};
  int k = s0 + sub;
  for (; k + 24 < e1; k += 32) {
    const s16x8 v0 = *(const s16x8*)(msg + ((size_t)k << 6) + 8 * c8);
    const s16x8 v1 = *(const s16x8*)(msg + ((size_t)(k + 8) << 6) + 8 * c8);
    const s16x8 v2 = *(const s16x8*)(msg + ((size_t)(k + 16) << 6) + 8 * c8);
    const s16x8 v3 = *(const s16x8*)(msg + ((size_t)(k + 24) << 6) + 8 * c8);
#pragma unroll
    for (int j = 0; j < 8; ++j) {
      a0[j] += bf2f(v0[j]); a1[j] += bf2f(v1[j]);
      a2[j] += bf2f(v2[j]); a3[j] += bf2f(v3[j]);
    }
  }
  for (; k < e1; k += 8) {
    const s16x8 v0 = *(const s16x8*)(msg + ((size_t)k << 6) + 8 * c8);
#pragma unroll
    for (int j = 0; j < 8; ++j) a0[j] += bf2f(v0[j]);
  }
#pragma unroll
  for (int j = 0; j < 8; ++j) {
    a0[j] += a1[j] + a2[j] + a3[j];
    a0[j] += __shfl_xor(a0[j], 8);
    a0[j] += __shfl_xor(a0[j], 16);
    a0[j] += __shfl_xor(a0[j], 32);
  }
  if (sub == 0) {
    float* dst = out + (size_t)NU * DD + (size_t)w * DD + 8 * c8;
    float4 o0 = {a0[0], a0[1], a0[2], a0[3]};
    float4 o1 = {a0[4], a0[5], a0[6], a0[7]};
    *(float4*)dst = o0;
    *(float4*)(dst + 4) = o1;
  }
}

// ---------------------------------------------------------------------------
// Gather-reduce, users: 8 lanes per user (avg deg 20), 32 users/block,
// 16 B/lane b128 loads, 4-deep unrolled.
// ---------------------------------------------------------------------------
__global__ __launch_bounds__(256) void gather_u_k(const int* __restrict__ off,
                                                  const short* __restrict__ msg,
                                                  float* __restrict__ out)
{
  const int u  = blockIdx.x * 32 + (threadIdx.x >> 3);    // user id
  const int c8 = threadIdx.x & 7;

  const int s0 = off[NM + u];
  const int e1 = off[NM + u + 1];

  float a0[8] = {0,0,0,0,0,0,0,0};
  float a1[8] = {0,0,0,0,0,0,0,0};
  float a2[8] = {0,0,0,0,0,0,0,0};
  float a3[8] = {0,0,0,0,0,0,0,0};
  int k = s0;
  for (; k + 3 < e1; k += 4) {
    const s16x8 v0 = *(const s16x8*)(msg + ((size_t)k << 6) + 8 * c8);
    const s16x8 v1 = *(const s16x8*)(msg + ((size_t)(k + 1) << 6) + 8 * c8);
    const s16x8 v2 = *(const s16x8*)(msg + ((size_t)(k + 2) << 6) + 8 * c8);
    const s16x8 v3 = *(const s16x8*)(msg + ((size_t)(k + 3) << 6) + 8 * c8);
#pragma unroll
    for (int j = 0; j < 8; ++j) {
      a0[j] += bf2f(v0[j]); a1[j] += bf2f(v1[j]);
      a2[j] += bf2f(v2[j]); a3[j] += bf2f(v3[j]);
    }
  }
  for (; k < e1; ++k) {
    const s16x8 v0 = *(const s16x8*)(msg + ((size_t)k << 6) + 8 * c8);
#pragma unroll
    for (int j = 0; j < 8; ++j) a0[j] += bf2f(v0[j]);
  }
  float* dst = out + (size_t)u * DD + 8 * c8;
  float4 o0, o1;
  o0.x = a0[0] + a1[0] + a2[0] + a3[0];
  o0.y = a0[1] + a1[1] + a2[1] + a3[1];
  o0.z = a0[2] + a1[2] + a2[2] + a3[2];
  o0.w = a0[3] + a1[3] + a2[3] + a3[3];
  o1.x = a0[4] + a1[4] + a2[4] + a3[4];
  o1.y = a0[5] + a1[5] + a2[5] + a3[5];
  o1.z = a0[6] + a1[6] + a2[6] + a3[6];
  o1.w = a0[7] + a1[7] + a2[7] + a3[7];
  *(float4*)dst = o0;
  *(float4*)(dst + 4) = o1;
}

// ---------------------------------------------------------------------------
// FC kernel (in-place on d_out): row -> gelu(row*ci) @ W.T + b, 16 rows/wave.
// ---------------------------------------------------------------------------
__global__ __launch_bounds__(256) void gcmc_fc(
    float* __restrict__ out,
    const float* __restrict__ user_ci, const float* __restrict__ movie_ci,
    const float* __restrict__ ufc_w, const float* __restrict__ ufc_b,
    const float* __restrict__ ifc_w, const float* __restrict__ ifc_b)
{
  const int wt   = blockIdx.x * 4 + (threadIdx.x >> 6);
  const int lane = threadIdx.x & 63;
  const int c    = lane & 15;
  const int kr   = lane >> 4;
  const bool isU = wt < (NU / 16);
  float* base        = isU ? out : out + (size_t)NU * DD;
  const float* ci    = isU ? user_ci : movie_ci;
  const float* W     = isU ? ufc_w : ifc_w;
  const float* bias  = isU ? ufc_b : ifc_b;
  const int row0 = (isU ? wt : wt - (NU / 16)) * 16;

  bf16x8 B[4][2];
#pragma unroll
  for (int t = 0; t < 4; ++t)
#pragma unroll
    for (int s = 0; s < 2; ++s)
      B[t][s] = cvt8(W + (size_t)(4 * c + t) * DD + s * 32 + kr * 8);

  const float civ = ci[row0 + c];
  const float* arow = base + (size_t)(row0 + c) * DD + kr * 8;

  bf16x8 A0, A1;
  {
    const float4 a = *(const float4*)arow;
    const float4 b = *(const float4*)(arow + 4);
    const float4 a2 = *(const float4*)(arow + 32);
    const float4 b2 = *(const float4*)(arow + 36);
    A0[0] = f2bf(gelu(a.x * civ));  A0[1] = f2bf(gelu(a.y * civ));
    A0[2] = f2bf(gelu(a.z * civ));  A0[3] = f2bf(gelu(a.w * civ));
    A0[4] = f2bf(gelu(b.x * civ));  A0[5] = f2bf(gelu(b.y * civ));
    A0[6] = f2bf(gelu(b.z * civ));  A0[7] = f2bf(gelu(b.w * civ));
    A1[0] = f2bf(gelu(a2.x * civ)); A1[1] = f2bf(gelu(a2.y * civ));
    A1[2] = f2bf(gelu(a2.z * civ)); A1[3] = f2bf(gelu(a2.w * civ));
    A1[4] = f2bf(gelu(b2.x * civ)); A1[5] = f2bf(gelu(b2.y * civ));
    A1[6] = f2bf(gelu(b2.z * civ)); A1[7] = f2bf(gelu(b2.w * civ));
  }

  f32x4 z4 = {0.f, 0.f, 0.f, 0.f};
  f32x4 C[4];
#pragma unroll
  for (int t = 0; t < 4; ++t) {
    C[t] = z4;
    C[t] = __builtin_amdgcn_mfma_f32_16x16x32_bf16(A0, B[t][0], C[t], 0, 0, 0);
    C[t] = __builtin_amdgcn_mfma_f32_16x16x32_bf16(A1, B[t][1], C[t], 0, 0, 0);
  }

  const float4 b4 = *(const float4*)(bias + 4 * c);
#pragma unroll
  for (int q = 0; q < 4; ++q) {
    const int row = row0 + kr * 4 + q;
    float4 o;
    o.x = C[0][q] + b4.x; o.y = C[1][q] + b4.y;
    o.z = C[2][q] + b4.z; o.w = C[3][q] + b4.w;
    *(float4*)(base + (size_t)row * DD + 4 * c) = o;
  }
}

extern "C" void kernel_launch(void* const* d_in, const int* in_sizes, int n_in,
                              void* d_out, int out_size, void* d_ws, size_t ws_size,
                              hipStream_t stream) {
  const int*   edges_u  = (const int*)  d_in[0];
  const int*   edges_m  = (const int*)  d_in[1];
  const float* rfeat    = (const float*)d_in[2];
  const float* W_user   = (const float*)d_in[3];
  const float* W_movie  = (const float*)d_in[4];
  const float* ps_u     = (const float*)d_in[5];
  const float* rs_u     = (const float*)d_in[6];
  const float* rw_u     = (const float*)d_in[7];
  const float* ps_m     = (const float*)d_in[8];
  const float* rs_m     = (const float*)d_in[9];
  const float* rw_m     = (const float*)d_in[10];
  const float* user_cj  = (const float*)d_in[11];
  const float* user_ci  = (const float*)d_in[12];
  const float* movie_cj = (const float*)d_in[13];
  const float* movie_ci = (const float*)d_in[14];
  const float* ufc_w    = (const float*)d_in[15];
  const float* ufc_b    = (const float*)d_in[16];
  const float* ifc_w    = (const float*)d_in[17];
  const float* ifc_b    = (const float*)d_in[18];

  float* out = (float*)d_out;

  // ---- workspace layout ----
  char* ws = (char*)d_ws;
  size_t o = 0;
  auto alloc = [&](size_t bytes) { char* p = ws + o; o += (bytes + 255) & ~(size_t)255; return p; };
  int*   cnt    = (int*)  alloc(sizeof(int) * NNODE);
  int*   off    = (int*)  alloc(sizeof(int) * (NNODE + 1));
  int*   rank_m = (int*)  alloc(sizeof(int) * NE);
  int*   rank_u = (int*)  alloc(sizeof(int) * NE);
  short* msg    = (short*)alloc(sizeof(short) * (size_t)2 * NE * DD);   // 512 MB
  (void)ws_size;

  hipMemsetAsync(cnt, 0, sizeof(int) * NNODE, stream);
  rank0_k<<<(NE / 4 + 255) / 256, 256, 0, stream>>>(edges_u, edges_m, cnt, rank_m, rank_u);
  scanoff_k<<<1, 1024, 0, stream>>>(cnt, off);

  dim3 g1((NTILE / 8 + 3) / 4, RR);   // (782, 5)
  gcmc_main<<<g1, 256, 0, stream>>>(edges_u, edges_m, rfeat, W_user, W_movie,
                                    ps_u, rs_u, rw_u, ps_m, rs_m, rw_m,
                                    user_cj, movie_cj, rank_m, rank_u, off, msg);

  gather_m_k<<<NM / 4, 256, 0, stream>>>(off, msg, out);
  gather_u_k<<<NU / 32, 256, 0, stream>>>(off, msg, out);

  gcmc_fc<<<(NNODE / 16) / 4, 256, 0, stream>>>(out, user_ci, movie_ci,
                                                ufc_w, ufc_b, ifc_w, ifc_b);
}